// Round 1
// baseline (4585.526 us; speedup 1.0000x reference)
//
#include <hip/hip_runtime.h>
#include <hip/hip_bf16.h>
#include <cstdint>
#include <cstddef>

#define D_DIM 512
#define B_DIM 8
#define S_DIM 4096
#define M_DIM (B_DIM * S_DIM)   // 32768 tokens
#define EPS_C 1e-6f

typedef __attribute__((ext_vector_type(8))) short bf16x8;
typedef __attribute__((ext_vector_type(4))) float f32x4;

__device__ __forceinline__ unsigned short f2bf(float f) {
  uint32_t u = __float_as_uint(f);
  u = (u + 0x7fffu + ((u >> 16) & 1u)) >> 16;   // RNE; inputs are finite
  return (unsigned short)u;
}
__device__ __forceinline__ float bf_lo(uint32_t u) { return __uint_as_float(u << 16); }
__device__ __forceinline__ float bf_hi(uint32_t u) { return __uint_as_float(u & 0xffff0000u); }
__device__ __forceinline__ float bf2f(unsigned short s) { return __uint_as_float(((uint32_t)s) << 16); }

// ---------------- fp32 -> bf16 conversion (vectorized, grid-stride) ----------------
__global__ void cvt_f32_bf16(const float* __restrict__ in, unsigned short* __restrict__ out, int n4) {
  int i = blockIdx.x * blockDim.x + threadIdx.x;
  int stride = gridDim.x * blockDim.x;
  for (; i < n4; i += stride) {
    float4 f = ((const float4*)in)[i];
    ushort4 o;
    o.x = f2bf(f.x); o.y = f2bf(f.y); o.z = f2bf(f.z); o.w = f2bf(f.w);
    ((ushort4*)out)[i] = o;
  }
}

// ---------------- fused projection GEMM: out[m][n] = act(sum_k X[m][k]*W[n][k] + b[n]) ----
// grid: (M/128, 512/128, 4 projections). 256 threads = 4 waves, each wave does 64x64
// via 4x4 grid of 16x16x32 bf16 MFMAs. BK=32 (one MFMA K-step per chunk).
#define TM 128
#define TN 128
#define BK 32
#define BKP 40   // padded LDS row stride (elements); rows stay 16B-aligned

__global__ __launch_bounds__(256) void proj_gemm(
    const unsigned short* __restrict__ Xb,   // [M][512] bf16 bits
    const unsigned short* __restrict__ Wb,   // [4][512][512] bf16 bits (row-major [n][k])
    const float* __restrict__ bq, const float* __restrict__ bk,
    const float* __restrict__ bv, const float* __restrict__ ba,
    unsigned short* __restrict__ q_ws, unsigned short* __restrict__ k_ws,
    unsigned short* __restrict__ v_ws, float* __restrict__ a_ws) {
  __shared__ unsigned short As[TM * BKP];
  __shared__ unsigned short Bs[TN * BKP];

  const int proj = blockIdx.z;
  const unsigned short* W = Wb + (size_t)proj * D_DIM * D_DIM;
  const int m0 = blockIdx.x * TM;
  const int n0 = blockIdx.y * TN;
  const int tid = threadIdx.x;
  const int lane = tid & 63;
  const int wave = tid >> 6;
  const int wm = (wave & 1) * 64;
  const int wn = (wave >> 1) * 64;
  const int quad = lane >> 4;      // 0..3
  const int l16 = lane & 15;

  f32x4 acc[4][4];
#pragma unroll
  for (int i = 0; i < 4; ++i)
#pragma unroll
    for (int j = 0; j < 4; ++j) acc[i][j] = (f32x4){0.f, 0.f, 0.f, 0.f};

  const int rl = tid >> 2;          // 0..63 (row per staging pass; 2 passes of 64 rows)
  const int kl = (tid & 3) * 8;     // k offset, 8 bf16 = 16B per load

  for (int kc = 0; kc < D_DIM; kc += BK) {
    __syncthreads();  // previous chunk's fragment reads done
#pragma unroll
    for (int p = 0; p < 2; ++p) {
      int row = rl + p * 64;
      *(uint4*)&As[row * BKP + kl] = *(const uint4*)&Xb[(size_t)(m0 + row) * D_DIM + kc + kl];
      *(uint4*)&Bs[row * BKP + kl] = *(const uint4*)&W[(size_t)(n0 + row) * D_DIM + kc + kl];
    }
    __syncthreads();

    bf16x8 afr[4], bfr[4];
#pragma unroll
    for (int im = 0; im < 4; ++im)
      afr[im] = *(const bf16x8*)&As[(wm + im * 16 + l16) * BKP + quad * 8];
#pragma unroll
    for (int in = 0; in < 4; ++in)
      bfr[in] = *(const bf16x8*)&Bs[(wn + in * 16 + l16) * BKP + quad * 8];
#pragma unroll
    for (int im = 0; im < 4; ++im)
#pragma unroll
      for (int in = 0; in < 4; ++in)
        acc[im][in] = __builtin_amdgcn_mfma_f32_16x16x32_bf16(afr[im], bfr[in], acc[im][in], 0, 0, 0);
  }

  const float* bias = (proj == 0) ? bq : (proj == 1) ? bk : (proj == 2) ? bv : ba;
#pragma unroll
  for (int in = 0; in < 4; ++in) {
    int nn = n0 + wn + in * 16 + l16;
    float bn = bias[nn];
#pragma unroll
    for (int im = 0; im < 4; ++im) {
      int mmb = m0 + wm + im * 16 + quad * 4;
#pragma unroll
      for (int vv = 0; vv < 4; ++vv) {
        float val = acc[im][in][vv] + bn;
        size_t idx = (size_t)(mmb + vv) * D_DIM + nn;
        if (proj == 0) {
          val = fmaxf(val, 0.f);
          q_ws[idx] = f2bf(val);
        } else if (proj == 1) {
          val = fmaxf(val, 0.f);
          k_ws[idx] = f2bf(val);
        } else if (proj == 2) {
          v_ws[idx] = f2bf(val);
        } else {
          val = 1.f / (1.f + __expf(-val));
          a_ws[idx] = val;   // gate kept fp32: multiplicative errors compound over 4096 steps
        }
      }
    }
  }
}

// ---------------- gated linear-attention recurrence ----------------
// grid: 8 batches * 32 column-chunks = 256 blocks, 256 threads = 4 independent waves.
// wave owns 4 output columns j; lane owns i in [8*lane, 8*lane+8) -> 32 fp32 state regs.
// z/den replicated per wave (cheap) so there is NO __syncthreads in the t-loop.
__global__ __launch_bounds__(256) void recur(
    const unsigned short* __restrict__ q_ws,
    const unsigned short* __restrict__ k_ws,
    const unsigned short* __restrict__ v_ws,
    const float* __restrict__ a_ws,
    float* __restrict__ out) {
  const int b = blockIdx.x >> 5;
  const int chunk = blockIdx.x & 31;
  const int lane = threadIdx.x & 63;
  const int wave = threadIdx.x >> 6;
  const int j0 = chunk * 16 + wave * 4;
  const int i0 = lane * 8;
  const size_t base = (size_t)b * S_DIM * D_DIM;

  const unsigned short* qp = q_ws + base + i0;
  const unsigned short* kp = k_ws + base + i0;
  const float* ap = a_ws + base + i0;
  const unsigned short* vp = v_ws + base + j0;
  float* op = out + base + j0;

  float s[4][8];
  float z[8];
#pragma unroll
  for (int c = 0; c < 4; ++c)
#pragma unroll
    for (int r = 0; r < 8; ++r) s[c][r] = 0.f;
#pragma unroll
  for (int r = 0; r < 8; ++r) z[r] = 0.f;

  for (int t = 0; t < S_DIM; ++t) {
    uint4 qu = *(const uint4*)qp; qp += D_DIM;
    uint4 ku = *(const uint4*)kp; kp += D_DIM;
    float4 a0 = *(const float4*)ap;
    float4 a1 = *(const float4*)(ap + 4); ap += D_DIM;
    ushort4 vu = *(const ushort4*)vp; vp += D_DIM;

    float qf[8] = {bf_lo(qu.x), bf_hi(qu.x), bf_lo(qu.y), bf_hi(qu.y),
                   bf_lo(qu.z), bf_hi(qu.z), bf_lo(qu.w), bf_hi(qu.w)};
    float kf[8] = {bf_lo(ku.x), bf_hi(ku.x), bf_lo(ku.y), bf_hi(ku.y),
                   bf_lo(ku.z), bf_hi(ku.z), bf_lo(ku.w), bf_hi(ku.w)};
    float af[8] = {a0.x, a0.y, a0.z, a0.w, a1.x, a1.y, a1.z, a1.w};
    float vc[4] = {bf2f(vu.x), bf2f(vu.y), bf2f(vu.z), bf2f(vu.w)};

    // z update + den partial (redundant per wave; avoids any cross-wave sync)
    float dp = 0.f;
#pragma unroll
    for (int r = 0; r < 8; ++r) {
      z[r] = fmaf(af[r], z[r], kf[r]);
      dp = fmaf(qf[r], z[r], dp);
    }

    // state update + num partials: 3 VALU per state element
    float np0 = 0.f, np1 = 0.f, np2 = 0.f, np3 = 0.f;
#pragma unroll
    for (int r = 0; r < 8; ++r) {
      s[0][r] = fmaf(af[r], s[0][r], kf[r] * vc[0]);
      np0 = fmaf(qf[r], s[0][r], np0);
      s[1][r] = fmaf(af[r], s[1][r], kf[r] * vc[1]);
      np1 = fmaf(qf[r], s[1][r], np1);
      s[2][r] = fmaf(af[r], s[2][r], kf[r] * vc[2]);
      np2 = fmaf(qf[r], s[2][r], np2);
      s[3][r] = fmaf(af[r], s[3][r], kf[r] * vc[3]);
      np3 = fmaf(qf[r], s[3][r], np3);
    }

    // 5 independent 64-lane butterfly allreduces (ILP across them)
#pragma unroll
    for (int msk = 1; msk < 64; msk <<= 1) {
      dp  += __shfl_xor(dp, msk, 64);
      np0 += __shfl_xor(np0, msk, 64);
      np1 += __shfl_xor(np1, msk, 64);
      np2 += __shfl_xor(np2, msk, 64);
      np3 += __shfl_xor(np3, msk, 64);
    }

    if (lane == 0) {
      float inv = 1.f / (dp + EPS_C);
      float4 o;
      o.x = np0 * inv; o.y = np1 * inv; o.z = np2 * inv; o.w = np3 * inv;
      *(float4*)op = o;
    }
    op += D_DIM;
  }
}

// ---------------- launch ----------------
extern "C" void kernel_launch(void* const* d_in, const int* in_sizes, int n_in,
                              void* d_out, int out_size, void* d_ws, size_t ws_size,
                              hipStream_t stream) {
  const float* x  = (const float*)d_in[0];
  const float* Wq = (const float*)d_in[1];
  const float* bq = (const float*)d_in[2];
  const float* Wk = (const float*)d_in[3];
  const float* bk = (const float*)d_in[4];
  const float* Wv = (const float*)d_in[5];
  const float* bv = (const float*)d_in[6];
  const float* Wa = (const float*)d_in[7];
  const float* ba = (const float*)d_in[8];
  float* out = (float*)d_out;

  uint8_t* w = (uint8_t*)d_ws;
  unsigned short* xb = (unsigned short*)w;  w += (size_t)M_DIM * D_DIM * 2;   // 33.5 MB
  unsigned short* wb = (unsigned short*)w;  w += (size_t)4 * D_DIM * D_DIM * 2; // 2.1 MB
  unsigned short* q_ws = (unsigned short*)w; w += (size_t)M_DIM * D_DIM * 2;
  unsigned short* k_ws = (unsigned short*)w; w += (size_t)M_DIM * D_DIM * 2;
  unsigned short* v_ws = (unsigned short*)w; w += (size_t)M_DIM * D_DIM * 2;
  float* a_ws = (float*)w;                   w += (size_t)M_DIM * D_DIM * 4;  // total ~203 MB

  cvt_f32_bf16<<<1024, 256, 0, stream>>>(x, xb, M_DIM * D_DIM / 4);
  cvt_f32_bf16<<<128, 256, 0, stream>>>(Wq, wb + 0 * D_DIM * D_DIM, D_DIM * D_DIM / 4);
  cvt_f32_bf16<<<128, 256, 0, stream>>>(Wk, wb + 1 * D_DIM * D_DIM, D_DIM * D_DIM / 4);
  cvt_f32_bf16<<<128, 256, 0, stream>>>(Wv, wb + 2 * D_DIM * D_DIM, D_DIM * D_DIM / 4);
  cvt_f32_bf16<<<128, 256, 0, stream>>>(Wa, wb + 3 * D_DIM * D_DIM, D_DIM * D_DIM / 4);

  proj_gemm<<<dim3(M_DIM / TM, D_DIM / TN, 4), 256, 0, stream>>>(
      xb, wb, bq, bk, bv, ba, q_ws, k_ws, v_ws, a_ws);

  recur<<<dim3(256), 256, 0, stream>>>(q_ws, k_ws, v_ws, a_ws, out);
}

// Round 3
// 863.040 us; speedup vs baseline: 5.3132x; 5.3132x over previous
//
#include <hip/hip_runtime.h>
#include <hip/hip_bf16.h>
#include <cstdint>
#include <cstddef>

#define D_DIM 512
#define B_DIM 8
#define S_DIM 4096
#define M_DIM (B_DIM * S_DIM)   // 32768 tokens
#define CHUNK 64
#define NCHUNK (S_DIM / CHUNK)  // 64 chunks per batch
#define EPS_C 1e-6f

typedef __attribute__((ext_vector_type(8))) short bf16x8;
typedef __attribute__((ext_vector_type(4))) float f32x4;

__device__ __forceinline__ unsigned short f2bf(float f) {
  uint32_t u = __float_as_uint(f);
  u = (u + 0x7fffu + ((u >> 16) & 1u)) >> 16;   // RNE; inputs finite
  return (unsigned short)u;
}
__device__ __forceinline__ float bf2f(unsigned short s) { return __uint_as_float(((uint32_t)s) << 16); }

// ---------------- fp32 -> bf16 conversion ----------------
__global__ void cvt_f32_bf16(const float* __restrict__ in, unsigned short* __restrict__ out, int n4) {
  int i = blockIdx.x * blockDim.x + threadIdx.x;
  int stride = gridDim.x * blockDim.x;
  for (; i < n4; i += stride) {
    float4 f = ((const float4*)in)[i];
    ushort4 o;
    o.x = f2bf(f.x); o.y = f2bf(f.y); o.z = f2bf(f.z); o.w = f2bf(f.w);
    ((ushort4*)out)[i] = o;
  }
}

// ---------------- fused projection GEMM (round-1 verified) ----------------
// Gate (proj==3) now stores the RAW PREACTIVATION as bf16; sigmoid happens in prep (fp32).
#define TM 128
#define TN 128
#define BK 32
#define BKP 40

__global__ __launch_bounds__(256) void proj_gemm(
    const unsigned short* __restrict__ Xb,
    const unsigned short* __restrict__ Wb,
    const float* __restrict__ bq, const float* __restrict__ bk,
    const float* __restrict__ bv, const float* __restrict__ ba,
    unsigned short* __restrict__ q_ws, unsigned short* __restrict__ k_ws,
    unsigned short* __restrict__ v_ws, unsigned short* __restrict__ g_ws) {
  __shared__ unsigned short As[TM * BKP];
  __shared__ unsigned short Bs[TN * BKP];

  const int proj = blockIdx.z;
  const unsigned short* W = Wb + (size_t)proj * D_DIM * D_DIM;
  const int m0 = blockIdx.x * TM;
  const int n0 = blockIdx.y * TN;
  const int tid = threadIdx.x;
  const int lane = tid & 63;
  const int wave = tid >> 6;
  const int wm = (wave & 1) * 64;
  const int wn = (wave >> 1) * 64;
  const int quad = lane >> 4;
  const int l16 = lane & 15;

  f32x4 acc[4][4];
#pragma unroll
  for (int i = 0; i < 4; ++i)
#pragma unroll
    for (int j = 0; j < 4; ++j) acc[i][j] = (f32x4){0.f, 0.f, 0.f, 0.f};

  const int rl = tid >> 2;
  const int kl = (tid & 3) * 8;

  for (int kc = 0; kc < D_DIM; kc += BK) {
    __syncthreads();
#pragma unroll
    for (int p = 0; p < 2; ++p) {
      int row = rl + p * 64;
      *(uint4*)&As[row * BKP + kl] = *(const uint4*)&Xb[(size_t)(m0 + row) * D_DIM + kc + kl];
      *(uint4*)&Bs[row * BKP + kl] = *(const uint4*)&W[(size_t)(n0 + row) * D_DIM + kc + kl];
    }
    __syncthreads();

    bf16x8 afr[4], bfr[4];
#pragma unroll
    for (int im = 0; im < 4; ++im)
      afr[im] = *(const bf16x8*)&As[(wm + im * 16 + l16) * BKP + quad * 8];
#pragma unroll
    for (int in = 0; in < 4; ++in)
      bfr[in] = *(const bf16x8*)&Bs[(wn + in * 16 + l16) * BKP + quad * 8];
#pragma unroll
    for (int im = 0; im < 4; ++im)
#pragma unroll
      for (int in = 0; in < 4; ++in)
        acc[im][in] = __builtin_amdgcn_mfma_f32_16x16x32_bf16(afr[im], bfr[in], acc[im][in], 0, 0, 0);
  }

  const float* bias = (proj == 0) ? bq : (proj == 1) ? bk : (proj == 2) ? bv : ba;
#pragma unroll
  for (int in = 0; in < 4; ++in) {
    int nn = n0 + wn + in * 16 + l16;
    float bn = bias[nn];
#pragma unroll
    for (int im = 0; im < 4; ++im) {
      int mmb = m0 + wm + im * 16 + quad * 4;
#pragma unroll
      for (int vv = 0; vv < 4; ++vv) {
        float val = acc[im][in][vv] + bn;
        size_t idx = (size_t)(mmb + vv) * D_DIM + nn;
        if (proj == 0) {
          q_ws[idx] = f2bf(fmaxf(val, 0.f));
        } else if (proj == 1) {
          k_ws[idx] = f2bf(fmaxf(val, 0.f));
        } else if (proj == 2) {
          v_ws[idx] = f2bf(val);
        } else {
          g_ws[idx] = f2bf(val);   // raw preact; sigmoid in prep (fp32 cumprod there)
        }
      }
    }
  }
}

// ---------------- prep: cum-factorized operands, LDS-free ----------------
// qt[r,i] = q*cum_r -> qt plane (fresh). kt[r,i] = k/cum_r -> ALIASES q plane
// (q[idx] read before kt[idx] write, same thread/iter). kh[r,i] = k*cum63/cum_r
// -> ALIASES k plane (same-index r-before-w). Af[i]=cum63, khs[i]=sum_r kh.
// NOTE: no __restrict__ — params alias by design.
__global__ __launch_bounds__(512) void prep(
    const unsigned short* q, const unsigned short* k, const unsigned short* g,
    unsigned short* qt, unsigned short* kt, unsigned short* kh,
    float* Af, float* khs) {
  const int c = blockIdx.x, b = blockIdx.y;
  const int i = threadIdx.x;
  const size_t t0 = (size_t)b * S_DIM + (size_t)c * CHUNK;
  float cum = 1.f;
  for (int r = 0; r < CHUNK; ++r) {
    float gv = bf2f(g[(t0 + r) * D_DIM + i]);
    cum *= 1.f / (1.f + __expf(-gv));
  }
  const float cum63 = cum;
  const size_t cb = ((size_t)b * NCHUNK + c) * D_DIM;
  Af[cb + i] = cum63;
  cum = 1.f;
  float s = 0.f;
  for (int r = 0; r < CHUNK; ++r) {
    size_t idx = (t0 + r) * D_DIM + i;
    float gv = bf2f(g[idx]);
    cum *= 1.f / (1.f + __expf(-gv));   // identical op sequence to pass 1
    float qv = bf2f(q[idx]);
    float kv = bf2f(k[idx]);
    qt[idx] = f2bf(qv * cum);
    float inv = 1.f / cum;
    kt[idx] = f2bf(kv * inv);
    float khf = kv * (cum63 * inv);     // <= k, no overflow
    kh[idx] = f2bf(khf);
    s += khf;
  }
  khs[cb + i] = s;
}

// ---------------- per-chunk transpose [r][i] -> [i][r], out-of-place, 33.8KB LDS ----
__global__ __launch_bounds__(256) void transpose_cd(
    const unsigned short* __restrict__ in, unsigned short* __restrict__ outT) {
  __shared__ unsigned short tile[CHUNK][264];   // 64 x 256 half-tile, padded
  const int c = blockIdx.x, b = blockIdx.y;
  const size_t base_in = ((size_t)b * S_DIM + (size_t)c * CHUNK) * D_DIM;
  const size_t base_out = ((size_t)b * NCHUNK + c) * (size_t)D_DIM * CHUNK;
  const int tid = threadIdx.x;
#pragma unroll
  for (int h = 0; h < 2; ++h) {
    if (h) __syncthreads();   // protect LDS reuse across halves
#pragma unroll
    for (int it = 0; it < 8; ++it) {
      int flat = (it * 256 + tid) * 8;   // 0..16383
      int row = flat >> 8;
      int col = flat & 255;
      *(uint4*)&tile[row][col] = *(const uint4*)&in[base_in + (size_t)row * D_DIM + h * 256 + col];
    }
    __syncthreads();
#pragma unroll
    for (int it = 0; it < 8; ++it) {
      int wq = it * 256 + tid;           // 0..2047
      int i_loc = wq >> 3;               // 0..255
      int r0 = (wq & 7) * 8;
      ushort4 v0, v1;
      v0.x = tile[r0 + 0][i_loc]; v0.y = tile[r0 + 1][i_loc];
      v0.z = tile[r0 + 2][i_loc]; v0.w = tile[r0 + 3][i_loc];
      v1.x = tile[r0 + 4][i_loc]; v1.y = tile[r0 + 5][i_loc];
      v1.z = tile[r0 + 6][i_loc]; v1.w = tile[r0 + 7][i_loc];
      size_t o = base_out + (size_t)(h * 256 + i_loc) * CHUNK + r0;
      *(ushort4*)&outT[o] = v0;
      *(ushort4*)&outT[o + 4] = v1;
    }
  }
}

// ---------------- intra-chunk: P = mask(qt·kt^T), rowsums, numI = P·V ----------------
// kt and numI alias the same plane (kt reads all precede the barrier; numI writes
// follow it; blocks touch disjoint rows) -> no __restrict__ on those.
__global__ __launch_bounds__(256) void intra(
    const unsigned short* __restrict__ qt, const unsigned short* kt,
    const unsigned short* __restrict__ VT,
    unsigned short* numI, float* __restrict__ rs) {
  __shared__ unsigned short P_lds[CHUNK][CHUNK + 8];
  const int c = blockIdx.x, b = blockIdx.y;
  const size_t t0 = (size_t)b * S_DIM + (size_t)c * CHUNK;
  const int lane = threadIdx.x & 63, w = threadIdx.x >> 6;
  const int l16 = lane & 15, q4 = lane >> 4;

  f32x4 accP[4];
#pragma unroll
  for (int n = 0; n < 4; ++n) accP[n] = (f32x4){0.f, 0.f, 0.f, 0.f};
#pragma unroll
  for (int ks = 0; ks < 16; ++ks) {
    bf16x8 afr = *(const bf16x8*)&qt[(t0 + 16 * w + l16) * D_DIM + 32 * ks + 8 * q4];
#pragma unroll
    for (int n = 0; n < 4; ++n) {
      bf16x8 bfr = *(const bf16x8*)&kt[(t0 + 16 * n + l16) * D_DIM + 32 * ks + 8 * q4];
      accP[n] = __builtin_amdgcn_mfma_f32_16x16x32_bf16(afr, bfr, accP[n], 0, 0, 0);
    }
  }
  float rsum[4] = {0.f, 0.f, 0.f, 0.f};
#pragma unroll
  for (int n = 0; n < 4; ++n) {
    int m = 16 * n + l16;
#pragma unroll
    for (int vv = 0; vv < 4; ++vv) {
      int r = 16 * w + 4 * q4 + vv;
      float pv = (m <= r) ? accP[n][vv] : 0.f;
      rsum[vv] += pv;
      P_lds[r][m] = f2bf(pv);
    }
  }
#pragma unroll
  for (int msk = 1; msk < 16; msk <<= 1) {
#pragma unroll
    for (int vv = 0; vv < 4; ++vv) rsum[vv] += __shfl_xor(rsum[vv], msk, 64);
  }
  if (l16 == 0) {
#pragma unroll
    for (int vv = 0; vv < 4; ++vv) rs[t0 + 16 * w + 4 * q4 + vv] = rsum[vv];
  }
  __syncthreads();
  bf16x8 pa0 = *(const bf16x8*)&P_lds[16 * w + l16][8 * q4];
  bf16x8 pa1 = *(const bf16x8*)&P_lds[16 * w + l16][32 + 8 * q4];
  const size_t vtb = ((size_t)b * NCHUNK + c) * (size_t)D_DIM * CHUNK;
#pragma unroll 4
  for (int nt = 0; nt < 32; ++nt) {
    bf16x8 b0 = *(const bf16x8*)&VT[vtb + (size_t)(nt * 16 + l16) * CHUNK + 8 * q4];
    bf16x8 b1 = *(const bf16x8*)&VT[vtb + (size_t)(nt * 16 + l16) * CHUNK + 32 + 8 * q4];
    f32x4 acc = (f32x4){0.f, 0.f, 0.f, 0.f};
    acc = __builtin_amdgcn_mfma_f32_16x16x32_bf16(pa0, b0, acc, 0, 0, 0);
    acc = __builtin_amdgcn_mfma_f32_16x16x32_bf16(pa1, b1, acc, 0, 0, 0);
#pragma unroll
    for (int vv = 0; vv < 4; ++vv)
      numI[(t0 + 16 * w + 4 * q4 + vv) * D_DIM + nt * 16 + l16] = f2bf(acc[vv]);
  }
}

// ---------------- zden: z-recurrence + invden. grid (8 row-groups, B) ----------------
// FIX vs round 2: publish z_prev BEFORE the chunk update — row r needs z from the
// previous chunk end (its own chunk's contribution is in rs via masked-P rowsums).
// rs and invden share one buffer (read-then-overwrite, same thread).
__global__ __launch_bounds__(512) void zden(
    const unsigned short* __restrict__ qt, const float* __restrict__ Af,
    const float* __restrict__ khs, float* rs_invden) {
  __shared__ float zlds[512];
  const int rb = blockIdx.x;          // row-group 0..7
  const int b = blockIdx.y;
  const int tid = threadIdx.x, lane = tid & 63, w = tid >> 6;
  float z = 0.f;                      // thread tid owns dim i = tid
  for (int c = 0; c < NCHUNK; ++c) {
    zlds[tid] = z;                    // z at end of chunk c-1
    __syncthreads();
    const size_t t0 = (size_t)b * S_DIM + (size_t)c * CHUNK;
    const int r = 8 * rb + w;
    bf16x8 qv = *(const bf16x8*)&qt[(t0 + r) * D_DIM + lane * 8];
    float4 z0 = *(const float4*)&zlds[lane * 8];
    float4 z1 = *(const float4*)&zlds[lane * 8 + 4];
    float p = 0.f;
    p = fmaf(bf2f((unsigned short)qv[0]), z0.x, p);
    p = fmaf(bf2f((unsigned short)qv[1]), z0.y, p);
    p = fmaf(bf2f((unsigned short)qv[2]), z0.z, p);
    p = fmaf(bf2f((unsigned short)qv[3]), z0.w, p);
    p = fmaf(bf2f((unsigned short)qv[4]), z1.x, p);
    p = fmaf(bf2f((unsigned short)qv[5]), z1.y, p);
    p = fmaf(bf2f((unsigned short)qv[6]), z1.z, p);
    p = fmaf(bf2f((unsigned short)qv[7]), z1.w, p);
#pragma unroll
    for (int msk = 1; msk < 64; msk <<= 1) p += __shfl_xor(p, msk, 64);
    const size_t cb = ((size_t)b * NCHUNK + c) * D_DIM;
    z = fmaf(Af[cb + tid], z, khs[cb + tid]);   // advance to end of chunk c
    if (lane == 0) {
      float* iv = &rs_invden[t0 + r];
      *iv = 1.f / (p + *iv + EPS_C);
    }
    __syncthreads();                  // zlds reads done before next publish
  }
}

// ---------------- scan: chunk-level state recurrence (MFMA), wave-specialized ----------
__global__ __launch_bounds__(512) void scan(
    const unsigned short* __restrict__ qt, const unsigned short* __restrict__ khT,
    const unsigned short* __restrict__ VT, const float* __restrict__ Af,
    const unsigned short* __restrict__ numI, const float* __restrict__ invden,
    float* __restrict__ out) {
  __shared__ unsigned short STj[16][520];  // S^T: [j_local][i] bf16
  const int jt = blockIdx.x, b = blockIdx.y;
  const int lane = threadIdx.x & 63, w = threadIdx.x >> 6;   // wave-uniform w
  const int l16 = lane & 15, q4 = lane >> 4;
  const int j0 = jt * 16;
  const bool is_state = (w >= 4);
  const int wv = w - 4;
  const int ib = 128 * wv;

  f32x4 acc[8];
#pragma unroll
  for (int T = 0; T < 8; ++T) acc[T] = (f32x4){0.f, 0.f, 0.f, 0.f};

  for (int c = 0; c < NCHUNK; ++c) {
    if (is_state) {
#pragma unroll
      for (int T = 0; T < 8; ++T) {
        uint2 pk;
        pk.x = (uint32_t)f2bf(acc[T][0]) | ((uint32_t)f2bf(acc[T][1]) << 16);
        pk.y = (uint32_t)f2bf(acc[T][2]) | ((uint32_t)f2bf(acc[T][3]) << 16);
        *(uint2*)&STj[l16][ib + 16 * T + 4 * q4] = pk;
      }
    }
    __syncthreads();
    const size_t cb = ((size_t)b * NCHUNK + c) * D_DIM;
    const size_t t0 = (size_t)b * S_DIM + (size_t)c * CHUNK;
    if (is_state) {
      // S = diag(Af) * S + kh^T V
#pragma unroll
      for (int T = 0; T < 8; ++T) {
        float4 af = *(const float4*)&Af[cb + ib + 16 * T + 4 * q4];
        acc[T][0] *= af.x; acc[T][1] *= af.y; acc[T][2] *= af.z; acc[T][3] *= af.w;
      }
      const size_t ob = cb * CHUNK;
      bf16x8 bv0 = *(const bf16x8*)&VT[ob + (size_t)(j0 + l16) * CHUNK + 8 * q4];
      bf16x8 bv1 = *(const bf16x8*)&VT[ob + (size_t)(j0 + l16) * CHUNK + 32 + 8 * q4];
#pragma unroll
      for (int T = 0; T < 8; ++T) {
        bf16x8 a0 = *(const bf16x8*)&khT[ob + (size_t)(ib + 16 * T + l16) * CHUNK + 8 * q4];
        bf16x8 a1 = *(const bf16x8*)&khT[ob + (size_t)(ib + 16 * T + l16) * CHUNK + 32 + 8 * q4];
        acc[T] = __builtin_amdgcn_mfma_f32_16x16x32_bf16(a0, bv0, acc[T], 0, 0, 0);
        acc[T] = __builtin_amdgcn_mfma_f32_16x16x32_bf16(a1, bv1, acc[T], 0, 0, 0);
      }
    } else {
      // numO = qt · S_prev, epilogue
      f32x4 accO = (f32x4){0.f, 0.f, 0.f, 0.f};
#pragma unroll
      for (int ks = 0; ks < 16; ++ks) {
        bf16x8 afr = *(const bf16x8*)&qt[(t0 + 16 * w + l16) * D_DIM + 32 * ks + 8 * q4];
        bf16x8 bfr = *(const bf16x8*)&STj[l16][32 * ks + 8 * q4];
        accO = __builtin_amdgcn_mfma_f32_16x16x32_bf16(afr, bfr, accO, 0, 0, 0);
      }
#pragma unroll
      for (int vv = 0; vv < 4; ++vv) {
        size_t t = t0 + 16 * w + 4 * q4 + vv;
        float nI = bf2f(numI[t * D_DIM + j0 + l16]);
        out[t * D_DIM + j0 + l16] = (accO[vv] + nI) * invden[t];
      }
    }
    __syncthreads();
  }
}

// ---------------- launch ----------------
extern "C" void kernel_launch(void* const* d_in, const int* in_sizes, int n_in,
                              void* d_out, int out_size, void* d_ws, size_t ws_size,
                              hipStream_t stream) {
  const float* x  = (const float*)d_in[0];
  const float* Wq = (const float*)d_in[1];
  const float* bq = (const float*)d_in[2];
  const float* Wk = (const float*)d_in[3];
  const float* bk = (const float*)d_in[4];
  const float* Wv = (const float*)d_in[5];
  const float* bv = (const float*)d_in[6];
  const float* Wa = (const float*)d_in[7];
  const float* ba = (const float*)d_in[8];
  float* out = (float*)d_out;

  // Workspace: 5 bf16 planes + weights + smalls = ~172 MB (< 194 MB proven in R1).
  // Alias chain: xb->qt | q_ws->kt->numI | k_ws->kh(->khT source) | v_ws->khT | g_ws->VT
  const size_t MD2 = (size_t)M_DIM * D_DIM * 2;
  uint8_t* w = (uint8_t*)d_ws;
  unsigned short* xb   = (unsigned short*)w; w += MD2;
  unsigned short* wb   = (unsigned short*)w; w += (size_t)4 * D_DIM * D_DIM * 2;
  unsigned short* q_ws = (unsigned short*)w; w += MD2;
  unsigned short* k_ws = (unsigned short*)w; w += MD2;
  unsigned short* v_ws = (unsigned short*)w; w += MD2;
  unsigned short* g_ws = (unsigned short*)w; w += MD2;
  float* Af     = (float*)w; w += (size_t)B_DIM * NCHUNK * D_DIM * 4;  // 1 MB
  float* khs    = (float*)w; w += (size_t)B_DIM * NCHUNK * D_DIM * 4;  // 1 MB
  float* invden = (float*)w; w += (size_t)M_DIM * 4;                   // 128 KB (rs then invden)

  unsigned short* qt   = xb;     // xb dead after proj_gemm
  unsigned short* kt   = q_ws;   // same-index overwrite inside prep
  unsigned short* kh   = k_ws;   // same-index overwrite inside prep
  unsigned short* VT   = g_ws;   // g dead after prep
  unsigned short* khT  = v_ws;   // v dead after its transpose
  unsigned short* numI = q_ws;   // kt dead after intra's P-phase (pre-barrier)

  cvt_f32_bf16<<<1024, 256, 0, stream>>>(x, xb, M_DIM * D_DIM / 4);
  cvt_f32_bf16<<<128, 256, 0, stream>>>(Wq, wb + 0 * D_DIM * D_DIM, D_DIM * D_DIM / 4);
  cvt_f32_bf16<<<128, 256, 0, stream>>>(Wk, wb + 1 * D_DIM * D_DIM, D_DIM * D_DIM / 4);
  cvt_f32_bf16<<<128, 256, 0, stream>>>(Wv, wb + 2 * D_DIM * D_DIM, D_DIM * D_DIM / 4);
  cvt_f32_bf16<<<128, 256, 0, stream>>>(Wa, wb + 3 * D_DIM * D_DIM, D_DIM * D_DIM / 4);

  proj_gemm<<<dim3(M_DIM / TM, D_DIM / TN, 4), 256, 0, stream>>>(
      xb, wb, bq, bk, bv, ba, q_ws, k_ws, v_ws, g_ws);

  prep<<<dim3(NCHUNK, B_DIM), 512, 0, stream>>>(q_ws, k_ws, g_ws, qt, kt, kh, Af, khs);
  transpose_cd<<<dim3(NCHUNK, B_DIM), 256, 0, stream>>>(v_ws, VT);
  transpose_cd<<<dim3(NCHUNK, B_DIM), 256, 0, stream>>>(kh, khT);
  intra<<<dim3(NCHUNK, B_DIM), 256, 0, stream>>>(qt, kt, VT, numI, invden);
  zden<<<dim3(8, B_DIM), 512, 0, stream>>>(qt, Af, khs, invden);
  scan<<<dim3(32, B_DIM), 512, 0, stream>>>(qt, khT, VT, Af, numI, invden, out);
}